// Round 5
// baseline (136.275 us; speedup 1.0000x reference)
//
#include <hip/hip_runtime.h>

// GNNDiscriminator: fully-fused single kernel, one graph per 128-thread block
// (2 waves). Grid 4096 blocks -> 16 blocks/CU -> 32 waves/CU (full occupancy),
// 2x the overlap of the 1-wave-per-graph version, half the per-thread edge work.
//
// Identities (outputs are only (out, gf)):
//   a_src[v] = x[v].u_src, u_src = W_lin@att_src ; a_dst likewise
//   a_edge[e] = eattr[e].we, we = W_edge@att_edge
//   softmax without max-shift (|alpha|<9 by weight scaling; fp32-safe,
//   normalized ratio identical; absmax headroom 10x)
//   gf = ((r^T x) @ W_lin)/V + b_gat,  r[s] = sum of attn weights leaving s

#define BB   4096
#define VV   32
#define FF   16
#define NBB  8
#define CC   128
#define EPER 256
constexpr int ERAND = BB * EPER;
constexpr int ETOT  = ERAND + BB * VV;
constexpr float SLOPE = 0.2f;

__launch_bounds__(128, 8)
__global__ void gnn_all(const float* __restrict__ x,
                        const int*   __restrict__ eidx,
                        const float* __restrict__ eattr,
                        const float* __restrict__ W_lin,
                        const float* __restrict__ att_src,
                        const float* __restrict__ att_dst,
                        const float* __restrict__ att_edge,
                        const float* __restrict__ W_edge,
                        const float* __restrict__ b_gat,
                        const float* __restrict__ W_out,
                        const float* __restrict__ b_out,
                        float* __restrict__ out,
                        float* __restrict__ gf_out)
{
  const int t    = threadIdx.x;           // 0..127
  const int lane = t & 63;
  const int g    = blockIdx.x;
  const int row  = t >> 2;                // owned x row 0..31
  const int q4   = t & 3;                 // feature quarter (4 floats)

  __shared__ float2 s_a[VV];              // {a_src, a_dst}
  __shared__ float  s_den[VV], s_r[VV];
  __shared__ float2 s_uv[FF];             // {u_src[f], u_dst[f]}
  __shared__ __align__(16) float s_we[NBB];
  __shared__ float  s_xt[FF * 33];        // transposed r-scaled x
  __shared__ __align__(16) float s_y[FF];
  __shared__ float  s_p[2];

  if (t < VV) { s_den[t] = 0.f; s_r[t] = 0.f; }
  if (t < FF) s_y[t] = 0.f;

  // ---- global loads, all issued up front ----
  const float4 xv = ((const float4*)(x + (size_t)(g * VV + row) * FF))[q4];

  int es[2], ed[2];
  float4 ea0[2], ea1[2];
  #pragma unroll
  for (int k = 0; k < 2; ++k) {
    const int e = g * EPER + 128 * k + t;
    es[k] = eidx[e] - g * VV;
    ed[k] = eidx[ETOT + e] - g * VV;
    const float4* ap = (const float4*)(eattr + (size_t)e * NBB);
    ea0[k] = ap[0]; ea1[k] = ap[1];
  }
  float4 la0 = {0,0,0,0}, la1 = {0,0,0,0};
  if (t >= 96) {                          // self-loop edge for node t-96
    const float4* lp = (const float4*)(eattr + (size_t)(ERAND + g * VV + (t - 96)) * NBB);
    la0 = lp[0]; la1 = lp[1];
  }

  // ---- projections: wave0 -> u_src/u_dst, wave1 -> we ----
  if (t < 64) {
    const int fu = lane & 15, q = lane >> 4;        // 4 C-chunks of 32
    const float4* wr = (const float4*)(W_lin + fu * CC + q * 32);
    const float4* as = (const float4*)(att_src + q * 32);
    const float4* ad = (const float4*)(att_dst + q * 32);
    float us = 0.f, ud = 0.f;
    #pragma unroll
    for (int j = 0; j < 8; ++j) {
      const float4 w = wr[j], a = as[j], d = ad[j];
      us += w.x*a.x + w.y*a.y + w.z*a.z + w.w*a.w;
      ud += w.x*d.x + w.y*d.y + w.z*d.z + w.w*d.w;
    }
    us += __shfl_xor(us, 16); us += __shfl_xor(us, 32);
    ud += __shfl_xor(ud, 16); ud += __shfl_xor(ud, 32);
    if (lane < FF) s_uv[lane] = make_float2(us, ud);
  } else {
    const int f8 = lane & 7, oct = lane >> 3;       // 8 C-chunks of 16
    const float4* wr = (const float4*)(W_edge + f8 * CC + oct * 16);
    const float4* ae = (const float4*)(att_edge + oct * 16);
    float pe = 0.f;
    #pragma unroll
    for (int j = 0; j < 4; ++j) {
      const float4 w = wr[j], a = ae[j];
      pe += w.x*a.x + w.y*a.y + w.z*a.z + w.w*a.w;
    }
    pe += __shfl_xor(pe, 8); pe += __shfl_xor(pe, 16); pe += __shfl_xor(pe, 32);
    if (lane < NBB) s_we[lane] = pe;
  }
  __syncthreads();

  // ---- a_src/a_dst: quarter-row dots, reduce over 4 lanes ----
  {
    const float xf[4] = {xv.x, xv.y, xv.z, xv.w};
    float a0 = 0.f, a1 = 0.f;
    #pragma unroll
    for (int j = 0; j < 4; ++j) {
      const float2 u = s_uv[q4 * 4 + j];
      a0 += xf[j] * u.x; a1 += xf[j] * u.y;
    }
    a0 += __shfl_xor(a0, 1); a0 += __shfl_xor(a0, 2);
    a1 += __shfl_xor(a1, 1); a1 += __shfl_xor(a1, 2);
    if (q4 == 0) s_a[row] = make_float2(a0, a1);
  }
  __syncthreads();

  // ---- phase B: ex = exp(leaky(alpha)), accumulate denom per dst ----
  const float4 w03 = *(const float4*)&s_we[0];
  const float4 w47 = *(const float4*)&s_we[4];
  float ex[3];
  #pragma unroll
  for (int k = 0; k < 2; ++k) {
    const float2 A = s_a[es[k]];
    const float2 D = s_a[ed[k]];
    const float aed = ea0[k].x*w03.x + ea0[k].y*w03.y + ea0[k].z*w03.z + ea0[k].w*w03.w
                    + ea1[k].x*w47.x + ea1[k].y*w47.y + ea1[k].z*w47.z + ea1[k].w*w47.w;
    const float a  = A.x + D.y + aed;
    const float al = a > 0.f ? a : SLOPE * a;
    ex[k] = __expf(al);
    atomicAdd(&s_den[ed[k]], ex[k]);
  }
  ex[2] = 0.f;
  if (t >= 96) {
    const int v = t - 96;
    const float2 S = s_a[v];
    const float aed = la0.x*w03.x + la0.y*w03.y + la0.z*w03.z + la0.w*w03.w
                    + la1.x*w47.x + la1.y*w47.y + la1.z*w47.z + la1.w*w47.w;
    const float a  = S.x + S.y + aed;
    const float al = a > 0.f ? a : SLOPE * a;
    ex[2] = __expf(al);
    atomicAdd(&s_den[v], ex[2]);
  }
  __syncthreads();

  // ---- phase C: r[src] += ex * rcp(denom[dst]) ----
  #pragma unroll
  for (int k = 0; k < 2; ++k)
    atomicAdd(&s_r[es[k]], ex[k] * __builtin_amdgcn_rcpf(s_den[ed[k]]));
  if (t >= 96) {
    const int v = t - 96;
    atomicAdd(&s_r[v], ex[2] * __builtin_amdgcn_rcpf(s_den[v]));
  }
  __syncthreads();

  // ---- phase D: y = r^T x / V via transposed scaled rows ----
  {
    const float rl = s_r[row];
    const float xf[4] = {xv.x, xv.y, xv.z, xv.w};
    #pragma unroll
    for (int j = 0; j < 4; ++j)
      s_xt[(q4 * 4 + j) * 33 + row] = xf[j] * rl;     // <=4-way banked
  }
  __syncthreads();
  {
    const int f = t & 15, part = t >> 4;              // 8 parts of 4 rows
    float yp = 0.f;
    #pragma unroll
    for (int j = 0; j < 4; ++j) yp += s_xt[f * 33 + part * 4 + j];
    yp += __shfl_xor(yp, 16); yp += __shfl_xor(yp, 32);  // wave's 4 parts
    if (lane < FF) atomicAdd(&s_y[lane], yp);            // 2-way: free
  }
  __syncthreads();

  // ---- gf = y @ W_lin + b_gat (1 channel/thread) ; out = gf.W_out + b_out ----
  const float4 y03 = *(const float4*)&s_y[0];
  const float4 y47 = *(const float4*)&s_y[4];
  const float4 y8b = *(const float4*)&s_y[8];
  const float4 ycf = *(const float4*)&s_y[12];
  const float yv[16] = {y03.x,y03.y,y03.z,y03.w, y47.x,y47.y,y47.z,y47.w,
                        y8b.x,y8b.y,y8b.z,y8b.w, ycf.x,ycf.y,ycf.z,ycf.w};
  float gx = b_gat[t];
  #pragma unroll
  for (int f = 0; f < FF; ++f)
    gx += (yv[f] * (1.0f / VV)) * W_lin[f * CC + t];  // coalesced, L1-hot
  gf_out[(size_t)g * CC + t] = gx;

  float p = gx * W_out[t];
  #pragma unroll
  for (int m = 1; m <= 32; m <<= 1) p += __shfl_xor(p, m);
  if (lane == 0) s_p[t >> 6] = p;
  __syncthreads();
  if (t == 0) out[g] = s_p[0] + s_p[1] + b_out[0];
}

extern "C" void kernel_launch(void* const* d_in, const int* in_sizes, int n_in,
                              void* d_out, int out_size, void* d_ws, size_t ws_size,
                              hipStream_t stream) {
  const float* x        = (const float*)d_in[0];
  const int*   eidx     = (const int*)  d_in[1];
  const float* eattr    = (const float*)d_in[2];
  const float* W_lin    = (const float*)d_in[3];
  const float* att_src  = (const float*)d_in[4];
  const float* att_dst  = (const float*)d_in[5];
  const float* att_edge = (const float*)d_in[6];
  const float* W_edge   = (const float*)d_in[7];
  const float* b_gat    = (const float*)d_in[8];
  const float* W_out    = (const float*)d_in[9];
  const float* b_out    = (const float*)d_in[10];

  float* out = (float*)d_out;        // [B,1] first, then gf [B,C]
  float* gf  = out + BB;

  gnn_all<<<dim3(BB), dim3(128), 0, stream>>>(
      x, eidx, eattr, W_lin, att_src, att_dst, att_edge, W_edge,
      b_gat, W_out, b_out, out, gf);
}

// Round 6
// 121.379 us; speedup vs baseline: 1.1227x; 1.1227x over previous
//
#include <hip/hip_runtime.h>

// GNNDiscriminator: fully-fused single kernel, one graph per 128-thread block
// (2 waves). Grid 4096 blocks -> 16 blocks/CU -> 32 waves/CU, 2 edges/thread.
//
// R5 post-mortem: __launch_bounds__(128,8) capped VGPR at 64 -> compiler
// squeezed to 32 and SPILLED the in-flight edge payload (WRITE_SIZE 2.2->40MB,
// kernel 41.8us). Fix: (128,4) -> cap 128 VGPR, actual ~60, no spill.
//
// Identities (outputs are only (out, gf)):
//   a_src[v] = x[v].u_src, u_src = W_lin@att_src ; a_dst likewise
//   a_edge[e] = eattr[e].we, we = W_edge@att_edge
//   softmax without max-shift (|alpha|<9 by weight scaling; fp32-safe,
//   normalized ratio identical; absmax headroom 10x)
//   gf = ((r^T x) @ W_lin)/V + b_gat,  r[s] = sum of attn weights leaving s

#define BB   4096
#define VV   32
#define FF   16
#define NBB  8
#define CC   128
#define EPER 256
constexpr int ERAND = BB * EPER;
constexpr int ETOT  = ERAND + BB * VV;
constexpr float SLOPE = 0.2f;

__launch_bounds__(128, 4)
__global__ void gnn_all(const float* __restrict__ x,
                        const int*   __restrict__ eidx,
                        const float* __restrict__ eattr,
                        const float* __restrict__ W_lin,
                        const float* __restrict__ att_src,
                        const float* __restrict__ att_dst,
                        const float* __restrict__ att_edge,
                        const float* __restrict__ W_edge,
                        const float* __restrict__ b_gat,
                        const float* __restrict__ W_out,
                        const float* __restrict__ b_out,
                        float* __restrict__ out,
                        float* __restrict__ gf_out)
{
  const int t    = threadIdx.x;           // 0..127
  const int lane = t & 63;
  const int g    = blockIdx.x;
  const int row  = t >> 2;                // owned x row 0..31
  const int q4   = t & 3;                 // feature quarter (4 floats)

  __shared__ float2 s_a[VV];              // {a_src, a_dst}
  __shared__ float  s_den[VV], s_r[VV];
  __shared__ float2 s_uv[FF];             // {u_src[f], u_dst[f]}
  __shared__ __align__(16) float s_we[NBB];
  __shared__ float  s_xt[FF * 33];        // transposed r-scaled x
  __shared__ __align__(16) float s_y[FF];
  __shared__ float  s_p[2];

  if (t < VV) { s_den[t] = 0.f; s_r[t] = 0.f; }
  if (t < FF) s_y[t] = 0.f;

  // ---- global loads, all issued up front ----
  const float4 xv = ((const float4*)(x + (size_t)(g * VV + row) * FF))[q4];

  int es[2], ed[2];
  float4 ea0[2], ea1[2];
  #pragma unroll
  for (int k = 0; k < 2; ++k) {
    const int e = g * EPER + 128 * k + t;
    es[k] = eidx[e] - g * VV;
    ed[k] = eidx[ETOT + e] - g * VV;
    const float4* ap = (const float4*)(eattr + (size_t)e * NBB);
    ea0[k] = ap[0]; ea1[k] = ap[1];
  }
  float4 la0 = {0,0,0,0}, la1 = {0,0,0,0};
  if (t >= 96) {                          // self-loop edge for node t-96
    const float4* lp = (const float4*)(eattr + (size_t)(ERAND + g * VV + (t - 96)) * NBB);
    la0 = lp[0]; la1 = lp[1];
  }

  // ---- projections: wave0 -> u_src/u_dst, wave1 -> we ----
  if (t < 64) {
    const int fu = lane & 15, q = lane >> 4;        // 4 C-chunks of 32
    const float4* wr = (const float4*)(W_lin + fu * CC + q * 32);
    const float4* as = (const float4*)(att_src + q * 32);
    const float4* ad = (const float4*)(att_dst + q * 32);
    float us = 0.f, ud = 0.f;
    #pragma unroll
    for (int j = 0; j < 8; ++j) {
      const float4 w = wr[j], a = as[j], d = ad[j];
      us += w.x*a.x + w.y*a.y + w.z*a.z + w.w*a.w;
      ud += w.x*d.x + w.y*d.y + w.z*d.z + w.w*d.w;
    }
    us += __shfl_xor(us, 16); us += __shfl_xor(us, 32);
    ud += __shfl_xor(ud, 16); ud += __shfl_xor(ud, 32);
    if (lane < FF) s_uv[lane] = make_float2(us, ud);
  } else {
    const int f8 = lane & 7, oct = lane >> 3;       // 8 C-chunks of 16
    const float4* wr = (const float4*)(W_edge + f8 * CC + oct * 16);
    const float4* ae = (const float4*)(att_edge + oct * 16);
    float pe = 0.f;
    #pragma unroll
    for (int j = 0; j < 4; ++j) {
      const float4 w = wr[j], a = ae[j];
      pe += w.x*a.x + w.y*a.y + w.z*a.z + w.w*a.w;
    }
    pe += __shfl_xor(pe, 8); pe += __shfl_xor(pe, 16); pe += __shfl_xor(pe, 32);
    if (lane < NBB) s_we[lane] = pe;
  }
  __syncthreads();

  // ---- a_src/a_dst: quarter-row dots, reduce over 4 lanes ----
  {
    const float xf[4] = {xv.x, xv.y, xv.z, xv.w};
    float a0 = 0.f, a1 = 0.f;
    #pragma unroll
    for (int j = 0; j < 4; ++j) {
      const float2 u = s_uv[q4 * 4 + j];
      a0 += xf[j] * u.x; a1 += xf[j] * u.y;
    }
    a0 += __shfl_xor(a0, 1); a0 += __shfl_xor(a0, 2);
    a1 += __shfl_xor(a1, 1); a1 += __shfl_xor(a1, 2);
    if (q4 == 0) s_a[row] = make_float2(a0, a1);
  }
  __syncthreads();

  // ---- phase B: ex = exp(leaky(alpha)), accumulate denom per dst ----
  const float4 w03 = *(const float4*)&s_we[0];
  const float4 w47 = *(const float4*)&s_we[4];
  float ex[3];
  #pragma unroll
  for (int k = 0; k < 2; ++k) {
    const float2 A = s_a[es[k]];
    const float2 D = s_a[ed[k]];
    const float aed = ea0[k].x*w03.x + ea0[k].y*w03.y + ea0[k].z*w03.z + ea0[k].w*w03.w
                    + ea1[k].x*w47.x + ea1[k].y*w47.y + ea1[k].z*w47.z + ea1[k].w*w47.w;
    const float a  = A.x + D.y + aed;
    const float al = a > 0.f ? a : SLOPE * a;
    ex[k] = __expf(al);
    atomicAdd(&s_den[ed[k]], ex[k]);
  }
  ex[2] = 0.f;
  if (t >= 96) {
    const int v = t - 96;
    const float2 S = s_a[v];
    const float aed = la0.x*w03.x + la0.y*w03.y + la0.z*w03.z + la0.w*w03.w
                    + la1.x*w47.x + la1.y*w47.y + la1.z*w47.z + la1.w*w47.w;
    const float a  = S.x + S.y + aed;
    const float al = a > 0.f ? a : SLOPE * a;
    ex[2] = __expf(al);
    atomicAdd(&s_den[v], ex[2]);
  }
  __syncthreads();

  // ---- phase C: r[src] += ex * rcp(denom[dst]) ----
  #pragma unroll
  for (int k = 0; k < 2; ++k)
    atomicAdd(&s_r[es[k]], ex[k] * __builtin_amdgcn_rcpf(s_den[ed[k]]));
  if (t >= 96) {
    const int v = t - 96;
    atomicAdd(&s_r[v], ex[2] * __builtin_amdgcn_rcpf(s_den[v]));
  }
  __syncthreads();

  // ---- phase D: y = r^T x / V via transposed scaled rows ----
  {
    const float rl = s_r[row];
    const float xf[4] = {xv.x, xv.y, xv.z, xv.w};
    #pragma unroll
    for (int j = 0; j < 4; ++j)
      s_xt[(q4 * 4 + j) * 33 + row] = xf[j] * rl;     // <=4-way banked
  }
  __syncthreads();
  {
    const int f = t & 15, part = t >> 4;              // 8 parts of 4 rows
    float yp = 0.f;
    #pragma unroll
    for (int j = 0; j < 4; ++j) yp += s_xt[f * 33 + part * 4 + j];
    yp += __shfl_xor(yp, 16); yp += __shfl_xor(yp, 32);  // wave's 4 parts
    if (lane < FF) atomicAdd(&s_y[lane], yp);            // 2 waves: 2 adds
  }
  __syncthreads();

  // ---- gf = y @ W_lin + b_gat (1 channel/thread) ; out = gf.W_out + b_out ----
  const float4 y03 = *(const float4*)&s_y[0];
  const float4 y47 = *(const float4*)&s_y[4];
  const float4 y8b = *(const float4*)&s_y[8];
  const float4 ycf = *(const float4*)&s_y[12];
  const float yv[16] = {y03.x,y03.y,y03.z,y03.w, y47.x,y47.y,y47.z,y47.w,
                        y8b.x,y8b.y,y8b.z,y8b.w, ycf.x,ycf.y,ycf.z,ycf.w};
  float gx = b_gat[t];
  #pragma unroll
  for (int f = 0; f < FF; ++f)
    gx += (yv[f] * (1.0f / VV)) * W_lin[f * CC + t];  // coalesced, L1-hot
  gf_out[(size_t)g * CC + t] = gx;

  float p = gx * W_out[t];
  #pragma unroll
  for (int m = 1; m <= 32; m <<= 1) p += __shfl_xor(p, m);
  if (lane == 0) s_p[t >> 6] = p;
  __syncthreads();
  if (t == 0) out[g] = s_p[0] + s_p[1] + b_out[0];
}

extern "C" void kernel_launch(void* const* d_in, const int* in_sizes, int n_in,
                              void* d_out, int out_size, void* d_ws, size_t ws_size,
                              hipStream_t stream) {
  const float* x        = (const float*)d_in[0];
  const int*   eidx     = (const int*)  d_in[1];
  const float* eattr    = (const float*)d_in[2];
  const float* W_lin    = (const float*)d_in[3];
  const float* att_src  = (const float*)d_in[4];
  const float* att_dst  = (const float*)d_in[5];
  const float* att_edge = (const float*)d_in[6];
  const float* W_edge   = (const float*)d_in[7];
  const float* b_gat    = (const float*)d_in[8];
  const float* W_out    = (const float*)d_in[9];
  const float* b_out    = (const float*)d_in[10];

  float* out = (float*)d_out;        // [B,1] first, then gf [B,C]
  float* gf  = out + BB;

  gnn_all<<<dim3(BB), dim3(128), 0, stream>>>(
      x, eidx, eattr, W_lin, att_src, att_dst, att_edge, W_edge,
      b_gat, W_out, b_out, out, gf);
}

// Round 7
// 119.487 us; speedup vs baseline: 1.1405x; 1.0158x over previous
//
#include <hip/hip_runtime.h>

// GNNDiscriminator: fully-fused single kernel. One WAVE per graph, 4 graphs
// per 256-thread block (best-known R4 structure: barrier-free per-wave
// phases). R6 experiment showed 2-wave blocks + higher occupancy do NOT beat
// this, so the change here is only: projections u_src/u_dst/we computed ONCE
// per block (wave0 -> u, wave1 -> we, one __syncthreads) instead of
// redundantly per wave (saves ~75% of the projection L1 traffic + VALU).
//
// Identities (outputs are only (out, gf)):
//   a_src[v] = x[v].u_src, u_src = W_lin@att_src ; a_dst likewise
//   a_edge[e] = eattr[e].we, we = W_edge@att_edge
//   softmax without max-shift (|alpha|<9 by weight scaling; fp32-safe,
//   normalized ratio identical; absmax headroom ~10x)
//   gf = ((r^T x) @ W_lin)/V + b_gat,  r[s] = sum of attn weights leaving s

#define BB   4096
#define VV   32
#define FF   16
#define NBB  8
#define CC   128
#define EPER 256
constexpr int ERAND = BB * EPER;
constexpr int ETOT  = ERAND + BB * VV;
constexpr float SLOPE = 0.2f;

__launch_bounds__(256, 4)
__global__ void gnn_all(const float* __restrict__ x,
                        const int*   __restrict__ eidx,
                        const float* __restrict__ eattr,
                        const float* __restrict__ W_lin,
                        const float* __restrict__ att_src,
                        const float* __restrict__ att_dst,
                        const float* __restrict__ att_edge,
                        const float* __restrict__ W_edge,
                        const float* __restrict__ b_gat,
                        const float* __restrict__ W_out,
                        const float* __restrict__ b_out,
                        float* __restrict__ out,
                        float* __restrict__ gf_out)
{
  const int t    = threadIdx.x;
  const int lane = t & 63;
  const int wave = __builtin_amdgcn_readfirstlane(t) >> 6;   // uniform
  const int g    = blockIdx.x * 4 + wave;
  const int half = lane >> 5;          // 0/1: feature half of the owned row
  const int v    = lane & 31;          // owned node

  __shared__ float2 s_a[4][VV];                    // {a_src, a_dst}
  __shared__ float  s_den[4][VV];
  __shared__ float  s_r[4][VV];
  __shared__ float  s_xt[4][FF * 33];              // transposed r-scaled x
  __shared__ __align__(16) float s_y[4][FF];
  __shared__ float2 s_uv[FF];                      // block-shared {u_src,u_dst}
  __shared__ __align__(16) float s_we[NBB];        // block-shared we

  // ---- global loads, all issued up front ----
  // x row v, split: this lane holds features half*8 .. half*8+7
  float4 xa, xb;
  {
    const float* xp = x + (size_t)(g * VV + v) * FF + half * 8;
    xa = ((const float4*)xp)[0]; xb = ((const float4*)xp)[1];
  }
  // 4 edges per lane, lane-interleaved (fully coalesced)
  int es[4], ed[4];
  float4 ea0[4], ea1[4];
  #pragma unroll
  for (int k = 0; k < 4; ++k) {
    const int e = g * EPER + 64 * k + lane;
    es[k] = eidx[e] - g * VV;
    ed[k] = eidx[ETOT + e] - g * VV;
    const float4* ap = (const float4*)(eattr + (size_t)e * NBB);
    ea0[k] = ap[0]; ea1[k] = ap[1];
  }
  // self-loop edge for node v: upper half-wave
  float4 la0 = {0,0,0,0}, la1 = {0,0,0,0};
  if (half) {
    const float4* lp = (const float4*)(eattr + (size_t)(ERAND + g * VV + v) * NBB);
    la0 = lp[0]; la1 = lp[1];
  }

  // ---- block-shared projections: wave0 -> u_src/u_dst, wave1 -> we ----
  if (wave == 0) {
    const int fu = lane & 15, q = lane >> 4;       // 4 C-chunks of 32
    const float4* wr = (const float4*)(W_lin + fu * CC + q * 32);
    const float4* as = (const float4*)(att_src + q * 32);
    const float4* ad = (const float4*)(att_dst + q * 32);
    float us = 0.f, ud = 0.f;
    #pragma unroll
    for (int j = 0; j < 8; ++j) {
      const float4 w = wr[j], a = as[j], d = ad[j];
      us += w.x*a.x + w.y*a.y + w.z*a.z + w.w*a.w;
      ud += w.x*d.x + w.y*d.y + w.z*d.z + w.w*d.w;
    }
    us += __shfl_xor(us, 16); us += __shfl_xor(us, 32);
    ud += __shfl_xor(ud, 16); ud += __shfl_xor(ud, 32);
    if (lane < FF) s_uv[lane] = make_float2(us, ud);
  } else if (wave == 1) {
    const int f8 = lane & 7, oct = lane >> 3;      // 8 C-chunks of 16
    const float4* wr = (const float4*)(W_edge + f8 * CC + oct * 16);
    const float4* ae = (const float4*)(att_edge + oct * 16);
    float pe = 0.f;
    #pragma unroll
    for (int j = 0; j < 4; ++j) {
      const float4 w = wr[j], a = ae[j];
      pe += w.x*a.x + w.y*a.y + w.z*a.z + w.w*a.w;
    }
    pe += __shfl_xor(pe, 8); pe += __shfl_xor(pe, 16); pe += __shfl_xor(pe, 32);
    if (lane < NBB) s_we[lane] = pe;
  }
  __syncthreads();   // only block-wide sync; all later phases are per-wave

  // ---- a_src/a_dst: half-row dot with u (LDS-broadcast), combine halves ----
  float a0 = 0.f, a1 = 0.f;
  {
    const float xr[8] = {xa.x, xa.y, xa.z, xa.w, xb.x, xb.y, xb.z, xb.w};
    #pragma unroll
    for (int j = 0; j < 8; ++j) {
      const float2 u = s_uv[half * 8 + j];         // 2 addrs/instr: conflict-free
      a0 += xr[j] * u.x; a1 += xr[j] * u.y;
    }
  }
  a0 += __shfl_xor(a0, 32); a1 += __shfl_xor(a1, 32);
  if (!half) {
    s_a[wave][v] = make_float2(a0, a1);
    s_den[wave][v] = 0.f; s_r[wave][v] = 0.f;
  }
  __threadfence_block();

  // ---- phase B: ex = exp(leaky(alpha)), accumulate denom per dst ----
  const float4 w03 = *(const float4*)&s_we[0];
  const float4 w47 = *(const float4*)&s_we[4];
  float ex[5];
  #pragma unroll
  for (int k = 0; k < 4; ++k) {
    const float2 A = s_a[wave][es[k]];
    const float2 D = s_a[wave][ed[k]];
    const float aed = ea0[k].x*w03.x + ea0[k].y*w03.y + ea0[k].z*w03.z + ea0[k].w*w03.w
                    + ea1[k].x*w47.x + ea1[k].y*w47.y + ea1[k].z*w47.z + ea1[k].w*w47.w;
    const float a  = A.x + D.y + aed;
    const float al = a > 0.f ? a : SLOPE * a;
    ex[k] = __expf(al);
    atomicAdd(&s_den[wave][ed[k]], ex[k]);
  }
  ex[4] = 0.f;
  if (half) {
    const float2 S = s_a[wave][v];
    const float aed = la0.x*w03.x + la0.y*w03.y + la0.z*w03.z + la0.w*w03.w
                    + la1.x*w47.x + la1.y*w47.y + la1.z*w47.z + la1.w*w47.w;
    const float a  = S.x + S.y + aed;
    const float al = a > 0.f ? a : SLOPE * a;
    ex[4] = __expf(al);
    atomicAdd(&s_den[wave][v], ex[4]);
  }
  __threadfence_block();

  // ---- phase C: r[src] += ex * rcp(denom[dst]) ----
  #pragma unroll
  for (int k = 0; k < 4; ++k)
    atomicAdd(&s_r[wave][es[k]], ex[k] * __builtin_amdgcn_rcpf(s_den[wave][ed[k]]));
  if (half)
    atomicAdd(&s_r[wave][v], ex[4] * __builtin_amdgcn_rcpf(s_den[wave][v]));
  __threadfence_block();

  // ---- phase D: y = r^T x / V via transposed scaled rows ----
  {
    const float rl = s_r[wave][v];                 // 2-way broadcast: free
    const float xr[8] = {xa.x, xa.y, xa.z, xa.w, xb.x, xb.y, xb.z, xb.w};
    #pragma unroll
    for (int j = 0; j < 8; ++j)
      s_xt[wave][(half * 8 + j) * 33 + v] = xr[j] * rl;
  }
  __threadfence_block();
  {
    const int fy = lane & 15, part = lane >> 4;
    float yp = 0.f;
    #pragma unroll
    for (int j = 0; j < 8; ++j) yp += s_xt[wave][fy * 33 + part * 8 + j];
    yp += __shfl_xor(yp, 16); yp += __shfl_xor(yp, 32);
    if (lane < FF) s_y[wave][lane] = yp * (1.0f / VV);
  }
  __threadfence_block();

  // ---- gf = y @ W_lin + b_gat ; out = gf . W_out + b_out ----
  const float4 y03 = *(const float4*)&s_y[wave][0];
  const float4 y47 = *(const float4*)&s_y[wave][4];
  const float4 y8b = *(const float4*)&s_y[wave][8];
  const float4 ycf = *(const float4*)&s_y[wave][12];
  const float yv[16] = {y03.x,y03.y,y03.z,y03.w, y47.x,y47.y,y47.z,y47.w,
                        y8b.x,y8b.y,y8b.z,y8b.w, ycf.x,ycf.y,ycf.z,ycf.w};
  const float2 bg = ((const float2*)b_gat)[lane];
  float gx = bg.x, gy = bg.y;
  const float2* W2 = (const float2*)W_lin;
  #pragma unroll
  for (int f = 0; f < FF; ++f) {
    const float2 w = W2[f * 64 + lane];            // L1-hot
    gx += yv[f] * w.x; gy += yv[f] * w.y;
  }
  ((float2*)(gf_out + (size_t)g * CC))[lane] = make_float2(gx, gy);

  const float2 wo = ((const float2*)W_out)[lane];
  float p = gx * wo.x + gy * wo.y;
  #pragma unroll
  for (int m = 1; m <= 32; m <<= 1) p += __shfl_xor(p, m);
  if (lane == 0) out[g] = p + b_out[0];
}

extern "C" void kernel_launch(void* const* d_in, const int* in_sizes, int n_in,
                              void* d_out, int out_size, void* d_ws, size_t ws_size,
                              hipStream_t stream) {
  const float* x        = (const float*)d_in[0];
  const int*   eidx     = (const int*)  d_in[1];
  const float* eattr    = (const float*)d_in[2];
  const float* W_lin    = (const float*)d_in[3];
  const float* att_src  = (const float*)d_in[4];
  const float* att_dst  = (const float*)d_in[5];
  const float* att_edge = (const float*)d_in[6];
  const float* W_edge   = (const float*)d_in[7];
  const float* b_gat    = (const float*)d_in[8];
  const float* W_out    = (const float*)d_in[9];
  const float* b_out    = (const float*)d_in[10];

  float* out = (float*)d_out;        // [B,1] first, then gf [B,C]
  float* gf  = out + BB;

  gnn_all<<<dim3(BB / 4), dim3(256), 0, stream>>>(
      x, eidx, eattr, W_lin, att_src, att_dst, att_edge, W_edge,
      b_gat, W_out, b_out, out, gf);
}